// Round 17
// baseline (412.432 us; speedup 1.0000x reference)
//
#include <hip/hip_runtime.h>
#include <hip/hip_fp16.h>
#include <math.h>

#define T 8
#define N 20000
#define E 320000
#define EPS 1e-5f
#define NBA 32         // agg-item sort blocks per t
#define CHUNKA 10000   // E/32 items per block
#define NPACK 10000    // N/2 packed u32 (2 x u16 counters)
#define TILES_PT 1250  // 16-node MFMA tiles per t
#define BW 625         // nodes per dst-bucket
#define NBUK 32        // dst-buckets per t
#define SPAN_MAX 13824 // LDS stage cap (mean span 10000, sigma ~100)

typedef _Float16 f16x8 __attribute__((ext_vector_type(8)));
typedef float f32x4 __attribute__((ext_vector_type(4)));

__device__ __forceinline__ float sigm(float x) { return 1.0f / (1.0f + expf(-x)); }
__device__ __forceinline__ float lo16f(unsigned int u) {
    unsigned short s = (unsigned short)(u & 0xffffu);
    return __half2float(*(__half*)&s);
}
__device__ __forceinline__ float hi16f(unsigned int u) {
    unsigned short s = (unsigned short)(u >> 16);
    return __half2float(*(__half*)&s);
}

// ---------------------------------------------------------------------------
// K0: W1t[j][k] = half(W1[k][j])  (fp16 transposed weights for MFMA B-frags)
__global__ __launch_bounds__(256) void k_prepw(const float* __restrict__ W1,
                                               __half* __restrict__ W1t) {
    int i = blockIdx.x * 256 + threadIdx.x;
    if (i >= 64 * 128) return;
    int j = i & 127, k = i >> 7;
    W1t[j * 64 + k] = __float2half(W1[i]);
}

// K1: partition pass (merged hist). One read of the keys produces BOTH the
// per-node packed histogram (-> hist_g for colsum) and per-bucket counts;
// a second read bins items (full dst<<15 | src) into LDS and writes the
// bucket-ordered run coalesced. Zero scattered global stores.
__global__ __launch_bounds__(1024) void k_partA(const int* __restrict__ edges,
                                                unsigned int* __restrict__ hist_g,
                                                unsigned int* __restrict__ bpart,
                                                int* __restrict__ bcnt) {
    __shared__ unsigned int arr[CHUNKA];   // 40 KB: hist, then stage
    __shared__ int cnt[NBUK], cur[NBUK];
    const int t = blockIdx.x & 7, b = blockIdx.x >> 3;
    const int tid = threadIdx.x;
    const int* keys = edges + (size_t)t * 2 * E + E + b * CHUNKA;   // dst
    const int* pays = edges + (size_t)t * 2 * E + b * CHUNKA;       // src
    for (int i = tid; i < NPACK; i += 1024) arr[i] = 0;
    if (tid < NBUK) cnt[tid] = 0;
    __syncthreads();
    for (int i = tid; i < CHUNKA; i += 1024) {
        int k = keys[i];
        atomicAdd(&arr[k >> 1], 1u << ((k & 1) * 16));
        atomicAdd(&cnt[k / BW], 1);
    }
    __syncthreads();
    unsigned int* hout = hist_g + (size_t)(t * NBA + b) * NPACK;
    for (int i = tid; i < NPACK; i += 1024) hout[i] = arr[i];
    if (tid == 0) {
        int run = 0;
        for (int u = 0; u < NBUK; u++) { cur[u] = run; run += cnt[u]; }
    }
    if (tid < NBUK) bcnt[(t * NBUK + tid) * NBUK + b] = cnt[tid];
    __syncthreads();
    for (int i = tid; i < CHUNKA; i += 1024) {
        int k = keys[i];
        int p = pays[i];
        int slot = atomicAdd(&cur[k / BW], 1);
        arr[slot] = ((unsigned int)k << 15) | (unsigned int)p;
    }
    __syncthreads();
    unsigned int* outp = bpart + (size_t)(t * NBUK + b) * CHUNKA;
    for (int i = tid; i < CHUNKA; i += 1024) outp[i] = arr[i];
}

// K2a: column sum over the 32 agg blocks — dega = in-degree; dinv.
__global__ __launch_bounds__(256) void k_colsum(
    const unsigned int* __restrict__ hist_g,
    int* __restrict__ dega, float* __restrict__ dinv) {
    int idx = blockIdx.x * 256 + threadIdx.x;
    if (idx >= T * NPACK) return;
    int t = idx / NPACK, i = idx - t * NPACK;
    const unsigned int* hp = hist_g + (size_t)t * NBA * NPACK + i;
    unsigned int a0 = 0, a1 = 0;
#pragma unroll
    for (int b = 0; b < NBA; b++) {
        unsigned int h = hp[(size_t)b * NPACK];
        a0 += h & 0xffffu; a1 += h >> 16;
    }
    int n0 = t * N + 2 * i;
    dega[n0]     = (int)a0;
    dega[n0 + 1] = (int)a1;
    dinv[n0]     = rsqrtf((float)a0 + 1.0f);
    dinv[n0 + 1] = rsqrtf((float)a1 + 1.0f);
}

// K2b: per-t exclusive prefix over node in-degrees -> offs (+ sentinel).
__global__ __launch_bounds__(1024) void k_scanN(const int* __restrict__ dega,
                                                int* __restrict__ offs) {
    const int t = blockIdx.x, tid = threadIdx.x;
    __shared__ int sh[1024];
    int local[20];
    int sum = 0;
    if (tid < 1000) {
        const int* tp = dega + t * N + tid * 20;
#pragma unroll
        for (int i = 0; i < 20; i++) { local[i] = tp[i]; sum += local[i]; }
    }
    sh[tid] = sum;
    __syncthreads();
    for (int off = 1; off < 1024; off <<= 1) {
        int v = (tid >= off) ? sh[tid - off] : 0;
        __syncthreads();
        sh[tid] += v;
        __syncthreads();
    }
    if (tid < 1000) {
        int run = t * E + sh[tid] - sum;
        int* op = offs + t * N + tid * 20;
#pragma unroll
        for (int i = 0; i < 20; i++) { op[i] = run; run += local[i]; }
    }
    if (t == T - 1 && tid == 0) offs[T * N] = T * E;
}

// K2d: xh[t][n][k] = half(dinv[t][n] * x[t][n][k]). per-t slice 2.56 MB.
__global__ __launch_bounds__(256) void k_cvt(const float* __restrict__ x,
                                             const float* __restrict__ dinv,
                                             __half* __restrict__ xh) {
    int idx = blockIdx.x * 256 + threadIdx.x;   // one float4 per thread
    if (idx >= T * N * 16) return;
    float d = dinv[idx >> 4];
    float4 vv = ((const float4*)x)[idx];
    __half h0 = __float2half(vv.x * d);
    __half h1 = __float2half(vv.y * d);
    __half h2 = __float2half(vv.z * d);
    __half h3 = __float2half(vv.w * d);
    ushort4 pack;
    pack.x = *(unsigned short*)&h0;
    pack.y = *(unsigned short*)&h1;
    pack.z = *(unsigned short*)&h2;
    pack.w = *(unsigned short*)&h3;
    ((ushort4*)xh)[idx] = pack;
}

// K3b: placement pass. One block per (t,bucket): gathers the bucket's items
// from the 32 per-block runs (coalesced reads), resolves CSR positions via
// 625 LDS cursors, stages the segment in LDS, writes it out as FULL LINES.
// Payload: src*32 (uint row offset for the half2 gather).
__global__ __launch_bounds__(1024) void k_place(const unsigned int* __restrict__ bpart,
                                                const int* __restrict__ bcnt,
                                                const int* __restrict__ offs,
                                                int* __restrict__ eidx) {
    __shared__ int stage[SPAN_MAX];          // 54 KB
    __shared__ int cursor[BW];
    __shared__ int offb[NBUK], lenb[NBUK];
    const int t = blockIdx.x & 7, u = blockIdx.x >> 3;
    const int tid = threadIdx.x;
    const int nodeBase = t * N + u * BW;
    const int dstBase = u * BW;
    const int segStart = offs[nodeBase];
    const int segEnd = offs[nodeBase + BW];
    const int span = segEnd - segStart;
    if (tid < NBUK) {
        int s = 0;
        for (int uu = 0; uu < u; uu++) s += bcnt[(t * NBUK + uu) * NBUK + tid];
        offb[tid] = s;
        lenb[tid] = bcnt[(t * NBUK + u) * NBUK + tid];
    }
    for (int j = tid; j < BW; j += 1024) cursor[j] = offs[nodeBase + j] - segStart;
    __syncthreads();
    if (span <= SPAN_MAX) {
        for (int b = 0; b < NBUK; b++) {
            const unsigned int* src = bpart + (size_t)(t * NBUK + b) * CHUNKA + offb[b];
            int len = lenb[b];
            for (int i = tid; i < len; i += 1024) {
                unsigned int it = src[i];
                int pos = atomicAdd(&cursor[(int)(it >> 15) - dstBase], 1);
                stage[pos] = (int)(it & 0x7fffu) << 5;
            }
            __syncthreads();
        }
        int* out = eidx + segStart;
        for (int i = tid; i < span; i += 1024) out[i] = stage[i];
    } else {                                  // statistically unreachable fallback
        for (int b = 0; b < NBUK; b++) {
            const unsigned int* src = bpart + (size_t)(t * NBUK + b) * CHUNKA + offb[b];
            int len = lenb[b];
            for (int i = tid; i < len; i += 1024) {
                unsigned int it = src[i];
                int pos = atomicAdd(&cursor[(int)(it >> 15) - dstBase], 1);
                eidx[segStart + pos] = (int)(it & 0x7fffu) << 5;
            }
            __syncthreads();
        }
    }
}

// K3c: w-sum from the coalesced bpart runs: wacc[src] += dinv[dst].
// One block per (t,b) run; LDS fp32 accumulator in two 10000-key halves.
__global__ __launch_bounds__(1024) void k_wsum(const unsigned int* __restrict__ bpart,
                                               const float* __restrict__ dinv,
                                               float* __restrict__ wpart) {
    __shared__ float wf[NPACK];              // 40 KB
    const int t = blockIdx.x & 7, b = blockIdx.x >> 3;
    const int tid = threadIdx.x;
    const unsigned int* run = bpart + (size_t)(t * NBUK + b) * CHUNKA;
    const float* dv = dinv + t * N;
    for (int half = 0; half < 2; half++) {
        for (int i = tid; i < NPACK; i += 1024) wf[i] = 0.f;
        __syncthreads();
        int lo = half * NPACK;
        for (int i = tid; i < CHUNKA; i += 1024) {
            unsigned int it = run[i];
            int q = (int)(it & 0x7fffu) - lo;
            if (q >= 0 && q < NPACK) atomicAdd(&wf[q], dv[it >> 15]);
        }
        __syncthreads();
        float* out = wpart + (size_t)(t * NBUK + b) * N + lo;
        for (int i = tid; i < NPACK; i += 1024) out[i] = wf[i];
        __syncthreads();
    }
}

// K3d: alpha[t][n] = dinv*(sum_b wpart + dinv). Coalesced 32-way reduce.
__global__ __launch_bounds__(256) void k_wred(const float* __restrict__ wpart,
                                              const float* __restrict__ dinv,
                                              float* __restrict__ alpha) {
    int node = blockIdx.x * 256 + threadIdx.x;
    if (node >= T * N) return;
    int t = node / N, n = node - t * N;
    float s = 0.f;
#pragma unroll
    for (int b = 0; b < NBUK; b++) s += wpart[(size_t)(t * NBUK + b) * N + n];
    float di = dinv[node];
    alpha[node] = di * (s + di);
}

// K4: gather — one wave per node; lane = (g = edge parity, f = feature pair).
// Each 4 B load fetches a half2 (2 features), so one wave processes 2 edges
// per pass: 3 inst/edge (shfl + load + 2cvt + 2add per pair). fp32 accum.
__global__ __launch_bounds__(256) void k_gather(
    const int* __restrict__ eidx, const int* __restrict__ offs,
    const float* __restrict__ dinv, const __half* __restrict__ xh,
    __half* __restrict__ vh) {
    const int t = blockIdx.x & 7;
    const int n = ((blockIdx.x >> 3) << 2) + (threadIdx.x >> 6);
    const int lane = threadIdx.x & 63;
    const int f = lane & 31, g = lane >> 5;
    if (n >= N) return;
    const int node = t * N + n;
    const int start = offs[node];
    const int end = offs[node + 1];
    const unsigned int* xt32 = (const unsigned int*)(xh + (size_t)t * N * 64);
    float acc0 = 0.f, acc1 = 0.f;
    for (int bs = start; bs < end; bs += 64) {
        int cnt = end - bs; if (cnt > 64) cnt = 64;
        int idx = 0;
        if (lane < cnt) idx = __builtin_nontemporal_load(&eidx[bs + lane]);
        int e = 0;
        for (; e + 15 < cnt; e += 16) {
            int o0 = __shfl(idx, e + 0 + g),  o1 = __shfl(idx, e + 2 + g);
            int o2 = __shfl(idx, e + 4 + g),  o3 = __shfl(idx, e + 6 + g);
            int o4 = __shfl(idx, e + 8 + g),  o5 = __shfl(idx, e + 10 + g);
            int o6 = __shfl(idx, e + 12 + g), o7 = __shfl(idx, e + 14 + g);
            unsigned int u0 = xt32[o0 + f], u1 = xt32[o1 + f];
            unsigned int u2 = xt32[o2 + f], u3 = xt32[o3 + f];
            unsigned int u4 = xt32[o4 + f], u5 = xt32[o5 + f];
            unsigned int u6 = xt32[o6 + f], u7 = xt32[o7 + f];
            acc0 += ((lo16f(u0) + lo16f(u1)) + (lo16f(u2) + lo16f(u3)))
                  + ((lo16f(u4) + lo16f(u5)) + (lo16f(u6) + lo16f(u7)));
            acc1 += ((hi16f(u0) + hi16f(u1)) + (hi16f(u2) + hi16f(u3)))
                  + ((hi16f(u4) + hi16f(u5)) + (hi16f(u6) + hi16f(u7)));
        }
        for (; e + 1 < cnt; e += 2) {
            int o = __shfl(idx, e + g);
            unsigned int u = xt32[o + f];
            acc0 += lo16f(u);
            acc1 += hi16f(u);
        }
        if (e < cnt) {
            int o = __shfl(idx, e);
            if (g == 0) {
                unsigned int u = xt32[o + f];
                acc0 += lo16f(u);
                acc1 += hi16f(u);
            }
        }
    }
    acc0 += __shfl_down(acc0, 32);
    acc1 += __shfl_down(acc1, 32);
    if (g == 0) {
        float di = dinv[node];
        unsigned int us = xt32[(n << 5) + f];
        float r0 = di * (acc0 + lo16f(us));
        float r1 = di * (acc1 + hi16f(us));
        __half h0 = __float2half(r0), h1 = __float2half(r1);
        unsigned int outp = ((unsigned int)(*(unsigned short*)&h1) << 16)
                          | (unsigned int)(*(unsigned short*)&h0);
        ((unsigned int*)vh)[(size_t)node * 32 + f] = outp;
    }
}

// K5: MFMA layer-1 GEMM (fp16 in, fp32 acc) + BN/ReLU + alpha-pool.
__global__ __launch_bounds__(256) void k_mfma_pool(
    const __half* __restrict__ vh, const float* __restrict__ alpha,
    const __half* __restrict__ W1t,
    const float* __restrict__ b1, const float* __restrict__ g1,
    const float* __restrict__ be1, const float* __restrict__ m1,
    const float* __restrict__ v1, float* __restrict__ pooled) {
    const int t = blockIdx.x & 7;
    const int bt = blockIdx.x >> 3;
    const int w = threadIdx.x >> 6, lane = threadIdx.x & 63;
    const int q = lane >> 4, col = lane & 15;
    const size_t tb = (size_t)t * N;

    f16x8 bfr[8][2];
    float sbv[8], stv[8];
#pragma unroll
    for (int jt = 0; jt < 8; jt++) {
        int j = jt * 16 + col;
        float s = g1[j] * rsqrtf(v1[j] + EPS);
        sbv[jt] = s;
        stv[jt] = s * b1[j] + be1[j] - m1[j] * s;
#pragma unroll
        for (int kk = 0; kk < 2; kk++)
            bfr[jt][kk] = *(const f16x8*)(W1t + (size_t)j * 64 + kk * 32 + q * 8);
    }
    float pool8[8];
#pragma unroll
    for (int jt = 0; jt < 8; jt++) pool8[jt] = 0.f;

    for (int i = 0; i < 8; i++) {
        int tau = bt * 32 + w * 8 + i;
        if (tau >= TILES_PT) break;
        int nb = tau * 16;
        const __half* vrow = vh + (tb + nb + col) * 64;
        f16x8 a0 = *(const f16x8*)(vrow + q * 8);
        f16x8 a1 = *(const f16x8*)(vrow + 32 + q * 8);
        float4 af = ((const float4*)(alpha + tb + nb))[q];
#pragma unroll
        for (int jt = 0; jt < 8; jt++) {
            f32x4 acc = {0.f, 0.f, 0.f, 0.f};
            acc = __builtin_amdgcn_mfma_f32_16x16x32_f16(a0, bfr[jt][0], acc, 0, 0, 0);
            acc = __builtin_amdgcn_mfma_f32_16x16x32_f16(a1, bfr[jt][1], acc, 0, 0, 0);
            float s = sbv[jt], sh = stv[jt];
            pool8[jt] += fmaxf(s * acc[0] + sh, 0.f) * af.x
                       + fmaxf(s * acc[1] + sh, 0.f) * af.y
                       + fmaxf(s * acc[2] + sh, 0.f) * af.z
                       + fmaxf(s * acc[3] + sh, 0.f) * af.w;
        }
    }
#pragma unroll
    for (int jt = 0; jt < 8; jt++) {
        pool8[jt] += __shfl_xor(pool8[jt], 16);
        pool8[jt] += __shfl_xor(pool8[jt], 32);
    }
    if (lane < 16) {
#pragma unroll
        for (int jt = 0; jt < 8; jt++)
            atomicAdd(&pooled[t * 128 + jt * 16 + lane], pool8[jt]);
    }
}

// K6a: warm every XCD's L2 with the recurrence weights (768 KB).
__global__ __launch_bounds__(256) void k_warm(const float* __restrict__ a,
                                              const float* __restrict__ b,
                                              const float* __restrict__ c,
                                              float* __restrict__ sink) {
    int slice = blockIdx.x >> 3;           // 0..7, 24576 floats each
    int start = slice * 24576;
    float s = 0.f;
    for (int i = start + threadIdx.x; i < start + 24576; i += 256) {
        float v;
        if (i < 65536) v = a[i];
        else if (i < 131072) v = b[i - 65536];
        else v = c[i - 131072];
        s += v;
    }
    sink[blockIdx.x * 256 + threadIdx.x] = s;
}

// K6b: emb = bn2(pooled/N @ W2 + b2) and layer-0 x-part gates.
__global__ __launch_bounds__(512) void k_emb(
    const float* __restrict__ pooled,
    const float* __restrict__ W2, const float* __restrict__ b2,
    const float* __restrict__ g2, const float* __restrict__ be2,
    const float* __restrict__ m2, const float* __restrict__ v2,
    const float* __restrict__ Wih0, const float* __restrict__ bih0,
    const float* __restrict__ bhh0, float* __restrict__ gx0_g) {
    const int t = blockIdx.x, tid = threadIdx.x;
    __shared__ float pm[128];
    __shared__ float es[128];
    if (tid < 128) pm[tid] = pooled[t * 128 + tid] * (1.0f / N);
    __syncthreads();
    if (tid < 128) {
        float s = g2[tid] * rsqrtf(v2[tid] + EPS);
        float sh = be2[tid] - m2[tid] * s;
        float dot = 0.f;
#pragma unroll 8
        for (int k = 0; k < 128; k++) dot += pm[k] * W2[k * 128 + tid];
        es[tid] = s * (dot + b2[tid]) + sh;
    }
    __syncthreads();
    float dot = bih0[tid] + bhh0[tid];
    const float4* w = (const float4*)(Wih0 + tid * 128);
    const float4* e4 = (const float4*)es;
#pragma unroll
    for (int k4 = 0; k4 < 32; k4++) {
        float4 a = w[k4], bb = e4[k4];
        dot += a.x * bb.x + a.y * bb.y + a.z * bb.z + a.w * bb.w;
    }
    gx0_g[t * 512 + tid] = dot;
}

// K6c: single block, 1024 threads. Thread (r = tid&511, hf = tid>>9) owns a
// HALF gate row (16 float4 = 64 VGPRs). Halves combine through LDS part[].
__global__ __launch_bounds__(1024, 4) void k_head(
    const float* __restrict__ gx0_g,
    const float* __restrict__ Whh0, const float* __restrict__ Whh1,
    const float* __restrict__ Wih1, const float* __restrict__ bih1,
    const float* __restrict__ bhh1,
    const float* __restrict__ Wc, const float* __restrict__ bc,
    float* __restrict__ out) {
    __shared__ float gx0[T][512];
    __shared__ float gx1h[2][T][512];
    __shared__ float ys[T][128];
    __shared__ float h[128];
    __shared__ float part[1024];
    const int tid = threadIdx.x;
    const int r = tid & 511, hf = tid >> 9;

    for (int i = tid; i < T * 512; i += 1024) gx0[i >> 9][i & 511] = gx0_g[i];
    if (tid < 128) h[tid] = 0.f;

    float4 w[16];
    {
        const float4* p = (const float4*)(Whh0 + r * 128 + hf * 64);
#pragma unroll
        for (int k = 0; k < 16; k++) w[k] = p[k];
    }
    float c = 0.f;
    __syncthreads();

    // LSTM layer 0
    for (int t = 0; t < T; t++) {
        const float4* h4 = ((const float4*)h) + hf * 16;
        float dot = 0.f;
#pragma unroll
        for (int k = 0; k < 16; k++) {
            float4 hv = h4[k];
            dot += w[k].x * hv.x + w[k].y * hv.y + w[k].z * hv.z + w[k].w * hv.w;
        }
        part[tid] = dot;
        __syncthreads();
        if (tid < 128) {
            float i_ = gx0[t][tid]       + part[tid]       + part[512 + tid];
            float f_ = gx0[t][128 + tid] + part[128 + tid] + part[640 + tid];
            float g_ = gx0[t][256 + tid] + part[256 + tid] + part[768 + tid];
            float o_ = gx0[t][384 + tid] + part[384 + tid] + part[896 + tid];
            c = sigm(f_) * c + sigm(i_) * tanhf(g_);
            float hv = sigm(o_) * tanhf(c);
            h[tid] = hv;
            ys[t][tid] = hv;
        }
        __syncthreads();
    }

    // gx1 halves
    {
        const float4* p = (const float4*)(Wih1 + r * 128 + hf * 64);
#pragma unroll
        for (int k = 0; k < 16; k++) w[k] = p[k];
        float bias = (hf == 0) ? (bih1[r] + bhh1[r]) : 0.f;
        for (int t = 0; t < T; t++) {
            const float4* y4 = ((const float4*)ys[t]) + hf * 16;
            float dot = bias;
#pragma unroll
            for (int k = 0; k < 16; k++) {
                float4 yv = y4[k];
                dot += w[k].x * yv.x + w[k].y * yv.y + w[k].z * yv.z + w[k].w * yv.w;
            }
            gx1h[hf][t][r] = dot;
        }
    }

    // LSTM layer 1
    {
        const float4* p = (const float4*)(Whh1 + r * 128 + hf * 64);
#pragma unroll
        for (int k = 0; k < 16; k++) w[k] = p[k];
    }
    if (tid < 128) h[tid] = 0.f;
    c = 0.f;
    __syncthreads();
    for (int t = 0; t < T; t++) {
        const float4* h4 = ((const float4*)h) + hf * 16;
        float dot = 0.f;
#pragma unroll
        for (int k = 0; k < 16; k++) {
            float4 hv = h4[k];
            dot += w[k].x * hv.x + w[k].y * hv.y + w[k].z * hv.z + w[k].w * hv.w;
        }
        part[tid] = dot;
        __syncthreads();
        if (tid < 128) {
            float i_ = gx1h[0][t][tid]       + gx1h[1][t][tid]       + part[tid]       + part[512 + tid];
            float f_ = gx1h[0][t][128 + tid] + gx1h[1][t][128 + tid] + part[128 + tid] + part[640 + tid];
            float g_ = gx1h[0][t][256 + tid] + gx1h[1][t][256 + tid] + part[256 + tid] + part[768 + tid];
            float o_ = gx1h[0][t][384 + tid] + gx1h[1][t][384 + tid] + part[384 + tid] + part[896 + tid];
            c = sigm(f_) * c + sigm(i_) * tanhf(g_);
            h[tid] = sigm(o_) * tanhf(c);
        }
        __syncthreads();
    }

    if (tid < 2) {
        float dot = bc[tid];
#pragma unroll 8
        for (int k = 0; k < 128; k++) dot += h[k] * Wc[tid * 128 + k];
        out[tid] = dot;
    }
    if (tid < 128) out[2 + tid] = h[tid];
}

// ---------------------------------------------------------------------------
extern "C" void kernel_launch(void* const* d_in, const int* in_sizes, int n_in,
                              void* d_out, int out_size, void* d_ws, size_t ws_size,
                              hipStream_t stream) {
    const float* x    = (const float*)d_in[0];
    const int*   edges= (const int*)d_in[1];
    const float* W1   = (const float*)d_in[2];
    const float* b1   = (const float*)d_in[3];
    const float* g1   = (const float*)d_in[4];
    const float* be1  = (const float*)d_in[5];
    const float* m1   = (const float*)d_in[6];
    const float* v1   = (const float*)d_in[7];
    const float* W2   = (const float*)d_in[8];
    const float* b2   = (const float*)d_in[9];
    const float* g2   = (const float*)d_in[10];
    const float* be2  = (const float*)d_in[11];
    const float* m2   = (const float*)d_in[12];
    const float* v2   = (const float*)d_in[13];
    const float* Wih0 = (const float*)d_in[14];
    const float* Whh0 = (const float*)d_in[15];
    const float* bih0 = (const float*)d_in[16];
    const float* bhh0 = (const float*)d_in[17];
    const float* Wih1 = (const float*)d_in[18];
    const float* Whh1 = (const float*)d_in[19];
    const float* bih1 = (const float*)d_in[20];
    const float* bhh1 = (const float*)d_in[21];
    const float* Wc   = (const float*)d_in[22];
    const float* bc   = (const float*)d_in[23];

    char* base = (char*)d_ws;
    // Aliasing: hist_g [0, 10.24 MB) dead after k_colsum; bpart
    // [10.24, 20.48 MB) written in k_partA, read by k_place AND k_wsum, then
    // dead; vh [0, 20.48 MB) written in k_gather (after colsum/place/wsum).
    unsigned int* hist_g = (unsigned int*)base;                       // T*NBA*NPACK u32
    unsigned int* bpart  = (unsigned int*)(base + (size_t)T * NBA * NPACK * 4);
    __half*       vh     = (__half*)base;                             // T*N*64 f16
    char* p = base + (size_t)T * NBA * NPACK * 4 + (size_t)T * NBUK * CHUNKA * 4;
    __half* xh   = (__half*)p;              p += (size_t)T * N * 64 * 2;  // 20.5 MB
    int*   offs  = (int*)p;                 p += (size_t)(T * N + 1) * 4 + 12; // keep 16B align
    int*   dega  = (int*)p;                 p += (size_t)T * N * 4;
    float* dinv  = (float*)p;               p += (size_t)T * N * 4;
    float* alpha = (float*)p;               p += (size_t)T * N * 4;
    int*   tot   = (int*)p;                 p += (size_t)T * N * 4;   // warm sink
    int*   eidx  = (int*)p;                 p += (size_t)T * E * 4;   // 10.25 MB
    float* wpart = (float*)p;               p += (size_t)T * NBUK * N * 4; // 20.5 MB
    int*   bcnt  = (int*)p;                 p += (size_t)T * NBUK * NBUK * 4;
    float* pooled= (float*)p;               p += (size_t)T * 128 * 4;
    float* gx0_g = (float*)p;               p += (size_t)T * 512 * 4;
    __half* W1t  = (__half*)p;

    (void)hipMemsetAsync(pooled, 0, T * 128 * sizeof(float), stream);

    k_prepw<<<32, 256, 0, stream>>>(W1, W1t);
    k_partA<<<T * NBUK, 1024, 0, stream>>>(edges, hist_g, bpart, bcnt);
    k_colsum<<<(T * NPACK + 255) / 256, 256, 0, stream>>>(hist_g, dega, dinv);
    k_scanN<<<T, 1024, 0, stream>>>(dega, offs);
    k_cvt<<<(T * N * 16 + 255) / 256, 256, 0, stream>>>(x, dinv, xh);
    k_place<<<T * NBUK, 1024, 0, stream>>>(bpart, bcnt, offs, eidx);
    k_wsum<<<T * NBUK, 1024, 0, stream>>>(bpart, dinv, wpart);
    k_wred<<<(T * N + 255) / 256, 256, 0, stream>>>(wpart, dinv, alpha);
    k_gather<<<(T * N) / 4, 256, 0, stream>>>(eidx, offs, dinv, xh, vh);
    k_mfma_pool<<<8 * 40, 256, 0, stream>>>(vh, alpha, W1t, b1, g1, be1, m1, v1, pooled);

    k_warm<<<64, 256, 0, stream>>>(Whh0, Whh1, Wih1, (float*)tot);
    k_emb<<<T, 512, 0, stream>>>(pooled, W2, b2, g2, be2, m2, v2, Wih0, bih0, bhh0, gx0_g);
    k_head<<<1, 1024, 0, stream>>>(gx0_g, Whh0, Whh1, Wih1, bih1, bhh1, Wc, bc, (float*)d_out);
}

// Round 18
// 391.735 us; speedup vs baseline: 1.0528x; 1.0528x over previous
//
#include <hip/hip_runtime.h>
#include <hip/hip_fp16.h>
#include <math.h>

#define T 8
#define N 20000
#define E 320000
#define EPS 1e-5f
#define NBA 32         // agg-item sort blocks per t
#define CHUNKA 10000   // E/32 items per block
#define NPACK 10000    // N/2 packed u32 (2 x u16 counters)
#define TILES_PT 1250  // 16-node MFMA tiles per t
#define BW 625         // nodes per dst-bucket
#define NBUK 32        // dst-buckets per t
#define SPAN_MAX 13824 // LDS stage cap (mean span 10000, sigma ~100)

typedef _Float16 f16x8 __attribute__((ext_vector_type(8)));
typedef float f32x4 __attribute__((ext_vector_type(4)));

__device__ __forceinline__ float sigm(float x) { return 1.0f / (1.0f + expf(-x)); }
__device__ __forceinline__ float lo16f(unsigned int u) {
    unsigned short s = (unsigned short)(u & 0xffffu);
    return __half2float(*(__half*)&s);
}
__device__ __forceinline__ float hi16f(unsigned int u) {
    unsigned short s = (unsigned short)(u >> 16);
    return __half2float(*(__half*)&s);
}

// ---------------------------------------------------------------------------
// K0: W1t[j][k] = half(W1[k][j])  (fp16 transposed weights for MFMA B-frags)
__global__ __launch_bounds__(256) void k_prepw(const float* __restrict__ W1,
                                               __half* __restrict__ W1t) {
    int i = blockIdx.x * 256 + threadIdx.x;
    if (i >= 64 * 128) return;
    int j = i & 127, k = i >> 7;
    W1t[j * 64 + k] = __float2half(W1[i]);
}

// K1: partition pass (merged hist). One read of the keys produces BOTH the
// per-node packed histogram (-> hist_g for colsum) and per-bucket counts;
// a second read bins items (full dst<<15 | src) into LDS and writes the
// bucket-ordered run coalesced. Zero scattered global stores.
__global__ __launch_bounds__(1024) void k_partA(const int* __restrict__ edges,
                                                unsigned int* __restrict__ hist_g,
                                                unsigned int* __restrict__ bpart,
                                                int* __restrict__ bcnt) {
    __shared__ unsigned int arr[CHUNKA];   // 40 KB: hist, then stage
    __shared__ int cnt[NBUK], cur[NBUK];
    const int t = blockIdx.x & 7, b = blockIdx.x >> 3;
    const int tid = threadIdx.x;
    const int* keys = edges + (size_t)t * 2 * E + E + b * CHUNKA;   // dst
    const int* pays = edges + (size_t)t * 2 * E + b * CHUNKA;       // src
    for (int i = tid; i < NPACK; i += 1024) arr[i] = 0;
    if (tid < NBUK) cnt[tid] = 0;
    __syncthreads();
    for (int i = tid; i < CHUNKA; i += 1024) {
        int k = keys[i];
        atomicAdd(&arr[k >> 1], 1u << ((k & 1) * 16));
        atomicAdd(&cnt[k / BW], 1);
    }
    __syncthreads();
    unsigned int* hout = hist_g + (size_t)(t * NBA + b) * NPACK;
    for (int i = tid; i < NPACK; i += 1024) hout[i] = arr[i];
    if (tid == 0) {
        int run = 0;
        for (int u = 0; u < NBUK; u++) { cur[u] = run; run += cnt[u]; }
    }
    if (tid < NBUK) bcnt[(t * NBUK + tid) * NBUK + b] = cnt[tid];
    __syncthreads();
    for (int i = tid; i < CHUNKA; i += 1024) {
        int k = keys[i];
        int p = pays[i];
        int slot = atomicAdd(&cur[k / BW], 1);
        arr[slot] = ((unsigned int)k << 15) | (unsigned int)p;
    }
    __syncthreads();
    unsigned int* outp = bpart + (size_t)(t * NBUK + b) * CHUNKA;
    for (int i = tid; i < CHUNKA; i += 1024) outp[i] = arr[i];
}

// K2a: column sum over the 32 agg blocks — dega = in-degree; dinv.
__global__ __launch_bounds__(256) void k_colsum(
    const unsigned int* __restrict__ hist_g,
    int* __restrict__ dega, float* __restrict__ dinv) {
    int idx = blockIdx.x * 256 + threadIdx.x;
    if (idx >= T * NPACK) return;
    int t = idx / NPACK, i = idx - t * NPACK;
    const unsigned int* hp = hist_g + (size_t)t * NBA * NPACK + i;
    unsigned int a0 = 0, a1 = 0;
#pragma unroll
    for (int b = 0; b < NBA; b++) {
        unsigned int h = hp[(size_t)b * NPACK];
        a0 += h & 0xffffu; a1 += h >> 16;
    }
    int n0 = t * N + 2 * i;
    dega[n0]     = (int)a0;
    dega[n0 + 1] = (int)a1;
    dinv[n0]     = rsqrtf((float)a0 + 1.0f);
    dinv[n0 + 1] = rsqrtf((float)a1 + 1.0f);
}

// K2b: per-t exclusive prefix over node in-degrees -> offs (+ sentinel).
__global__ __launch_bounds__(1024) void k_scanN(const int* __restrict__ dega,
                                                int* __restrict__ offs) {
    const int t = blockIdx.x, tid = threadIdx.x;
    __shared__ int sh[1024];
    int local[20];
    int sum = 0;
    if (tid < 1000) {
        const int* tp = dega + t * N + tid * 20;
#pragma unroll
        for (int i = 0; i < 20; i++) { local[i] = tp[i]; sum += local[i]; }
    }
    sh[tid] = sum;
    __syncthreads();
    for (int off = 1; off < 1024; off <<= 1) {
        int v = (tid >= off) ? sh[tid - off] : 0;
        __syncthreads();
        sh[tid] += v;
        __syncthreads();
    }
    if (tid < 1000) {
        int run = t * E + sh[tid] - sum;
        int* op = offs + t * N + tid * 20;
#pragma unroll
        for (int i = 0; i < 20; i++) { op[i] = run; run += local[i]; }
    }
    if (t == T - 1 && tid == 0) offs[T * N] = T * E;
}

// K2d: xh[t][n][k] = half(dinv[t][n] * x[t][n][k]). per-t slice 2.56 MB.
__global__ __launch_bounds__(256) void k_cvt(const float* __restrict__ x,
                                             const float* __restrict__ dinv,
                                             __half* __restrict__ xh) {
    int idx = blockIdx.x * 256 + threadIdx.x;   // one float4 per thread
    if (idx >= T * N * 16) return;
    float d = dinv[idx >> 4];
    float4 vv = ((const float4*)x)[idx];
    __half h0 = __float2half(vv.x * d);
    __half h1 = __float2half(vv.y * d);
    __half h2 = __float2half(vv.z * d);
    __half h3 = __float2half(vv.w * d);
    ushort4 pack;
    pack.x = *(unsigned short*)&h0;
    pack.y = *(unsigned short*)&h1;
    pack.z = *(unsigned short*)&h2;
    pack.w = *(unsigned short*)&h3;
    ((ushort4*)xh)[idx] = pack;
}

// K3b: placement pass. One block per (t,bucket): gathers the bucket's items
// from the 32 per-block runs (coalesced reads), resolves CSR positions via
// 625 LDS cursors, stages the segment in LDS, writes it out as FULL LINES.
// Payload: src*32 (uint row offset for the half2 gather).
__global__ __launch_bounds__(1024) void k_place(const unsigned int* __restrict__ bpart,
                                                const int* __restrict__ bcnt,
                                                const int* __restrict__ offs,
                                                int* __restrict__ eidx) {
    __shared__ int stage[SPAN_MAX];          // 54 KB
    __shared__ int cursor[BW];
    __shared__ int offb[NBUK], lenb[NBUK];
    const int t = blockIdx.x & 7, u = blockIdx.x >> 3;
    const int tid = threadIdx.x;
    const int nodeBase = t * N + u * BW;
    const int dstBase = u * BW;
    const int segStart = offs[nodeBase];
    const int segEnd = offs[nodeBase + BW];
    const int span = segEnd - segStart;
    if (tid < NBUK) {
        int s = 0;
        for (int uu = 0; uu < u; uu++) s += bcnt[(t * NBUK + uu) * NBUK + tid];
        offb[tid] = s;
        lenb[tid] = bcnt[(t * NBUK + u) * NBUK + tid];
    }
    for (int j = tid; j < BW; j += 1024) cursor[j] = offs[nodeBase + j] - segStart;
    __syncthreads();
    if (span <= SPAN_MAX) {
        for (int b = 0; b < NBUK; b++) {
            const unsigned int* src = bpart + (size_t)(t * NBUK + b) * CHUNKA + offb[b];
            int len = lenb[b];
            for (int i = tid; i < len; i += 1024) {
                unsigned int it = src[i];
                int pos = atomicAdd(&cursor[(int)(it >> 15) - dstBase], 1);
                stage[pos] = (int)(it & 0x7fffu) << 5;
            }
            __syncthreads();
        }
        int* out = eidx + segStart;
        for (int i = tid; i < span; i += 1024) out[i] = stage[i];
    } else {                                  // statistically unreachable fallback
        for (int b = 0; b < NBUK; b++) {
            const unsigned int* src = bpart + (size_t)(t * NBUK + b) * CHUNKA + offb[b];
            int len = lenb[b];
            for (int i = tid; i < len; i += 1024) {
                unsigned int it = src[i];
                int pos = atomicAdd(&cursor[(int)(it >> 15) - dstBase], 1);
                eidx[segStart + pos] = (int)(it & 0x7fffu) << 5;
            }
            __syncthreads();
        }
    }
}

// K3c: w-sum from the coalesced bpart runs: wacc[src] += dinv[dst].
__global__ __launch_bounds__(1024) void k_wsum(const unsigned int* __restrict__ bpart,
                                               const float* __restrict__ dinv,
                                               float* __restrict__ wpart) {
    __shared__ float wf[NPACK];              // 40 KB
    const int t = blockIdx.x & 7, b = blockIdx.x >> 3;
    const int tid = threadIdx.x;
    const unsigned int* run = bpart + (size_t)(t * NBUK + b) * CHUNKA;
    const float* dv = dinv + t * N;
    for (int half = 0; half < 2; half++) {
        for (int i = tid; i < NPACK; i += 1024) wf[i] = 0.f;
        __syncthreads();
        int lo = half * NPACK;
        for (int i = tid; i < CHUNKA; i += 1024) {
            unsigned int it = run[i];
            int q = (int)(it & 0x7fffu) - lo;
            if (q >= 0 && q < NPACK) atomicAdd(&wf[q], dv[it >> 15]);
        }
        __syncthreads();
        float* out = wpart + (size_t)(t * NBUK + b) * N + lo;
        for (int i = tid; i < NPACK; i += 1024) out[i] = wf[i];
        __syncthreads();
    }
}

// K3d: alpha[t][n] = dinv*(sum_b wpart + dinv). Coalesced 32-way reduce.
__global__ __launch_bounds__(256) void k_wred(const float* __restrict__ wpart,
                                              const float* __restrict__ dinv,
                                              float* __restrict__ alpha) {
    int node = blockIdx.x * 256 + threadIdx.x;
    if (node >= T * N) return;
    int t = node / N, n = node - t * N;
    float s = 0.f;
#pragma unroll
    for (int b = 0; b < NBUK; b++) s += wpart[(size_t)(t * NBUK + b) * N + n];
    float di = dinv[node];
    alpha[node] = di * (s + di);
}

// K4: gather — one wave per node; lane = (g = edge parity, f = feature pair).
__global__ __launch_bounds__(256) void k_gather(
    const int* __restrict__ eidx, const int* __restrict__ offs,
    const float* __restrict__ dinv, const __half* __restrict__ xh,
    __half* __restrict__ vh) {
    const int t = blockIdx.x & 7;
    const int n = ((blockIdx.x >> 3) << 2) + (threadIdx.x >> 6);
    const int lane = threadIdx.x & 63;
    const int f = lane & 31, g = lane >> 5;
    if (n >= N) return;
    const int node = t * N + n;
    const int start = offs[node];
    const int end = offs[node + 1];
    const unsigned int* xt32 = (const unsigned int*)(xh + (size_t)t * N * 64);
    float acc0 = 0.f, acc1 = 0.f;
    for (int bs = start; bs < end; bs += 64) {
        int cnt = end - bs; if (cnt > 64) cnt = 64;
        int idx = 0;
        if (lane < cnt) idx = __builtin_nontemporal_load(&eidx[bs + lane]);
        int e = 0;
        for (; e + 15 < cnt; e += 16) {
            int o0 = __shfl(idx, e + 0 + g),  o1 = __shfl(idx, e + 2 + g);
            int o2 = __shfl(idx, e + 4 + g),  o3 = __shfl(idx, e + 6 + g);
            int o4 = __shfl(idx, e + 8 + g),  o5 = __shfl(idx, e + 10 + g);
            int o6 = __shfl(idx, e + 12 + g), o7 = __shfl(idx, e + 14 + g);
            unsigned int u0 = xt32[o0 + f], u1 = xt32[o1 + f];
            unsigned int u2 = xt32[o2 + f], u3 = xt32[o3 + f];
            unsigned int u4 = xt32[o4 + f], u5 = xt32[o5 + f];
            unsigned int u6 = xt32[o6 + f], u7 = xt32[o7 + f];
            acc0 += ((lo16f(u0) + lo16f(u1)) + (lo16f(u2) + lo16f(u3)))
                  + ((lo16f(u4) + lo16f(u5)) + (lo16f(u6) + lo16f(u7)));
            acc1 += ((hi16f(u0) + hi16f(u1)) + (hi16f(u2) + hi16f(u3)))
                  + ((hi16f(u4) + hi16f(u5)) + (hi16f(u6) + hi16f(u7)));
        }
        for (; e + 1 < cnt; e += 2) {
            int o = __shfl(idx, e + g);
            unsigned int u = xt32[o + f];
            acc0 += lo16f(u);
            acc1 += hi16f(u);
        }
        if (e < cnt) {
            int o = __shfl(idx, e);
            if (g == 0) {
                unsigned int u = xt32[o + f];
                acc0 += lo16f(u);
                acc1 += hi16f(u);
            }
        }
    }
    acc0 += __shfl_down(acc0, 32);
    acc1 += __shfl_down(acc1, 32);
    if (g == 0) {
        float di = dinv[node];
        unsigned int us = xt32[(n << 5) + f];
        float r0 = di * (acc0 + lo16f(us));
        float r1 = di * (acc1 + hi16f(us));
        __half h0 = __float2half(r0), h1 = __float2half(r1);
        unsigned int outp = ((unsigned int)(*(unsigned short*)&h1) << 16)
                          | (unsigned int)(*(unsigned short*)&h0);
        ((unsigned int*)vh)[(size_t)node * 32 + f] = outp;
    }
}

// K5: MFMA layer-1 GEMM (fp16 in, fp32 acc) + BN/ReLU + alpha-pool.
__global__ __launch_bounds__(256) void k_mfma_pool(
    const __half* __restrict__ vh, const float* __restrict__ alpha,
    const __half* __restrict__ W1t,
    const float* __restrict__ b1, const float* __restrict__ g1,
    const float* __restrict__ be1, const float* __restrict__ m1,
    const float* __restrict__ v1, float* __restrict__ pooled) {
    const int t = blockIdx.x & 7;
    const int bt = blockIdx.x >> 3;
    const int w = threadIdx.x >> 6, lane = threadIdx.x & 63;
    const int q = lane >> 4, col = lane & 15;
    const size_t tb = (size_t)t * N;

    f16x8 bfr[8][2];
    float sbv[8], stv[8];
#pragma unroll
    for (int jt = 0; jt < 8; jt++) {
        int j = jt * 16 + col;
        float s = g1[j] * rsqrtf(v1[j] + EPS);
        sbv[jt] = s;
        stv[jt] = s * b1[j] + be1[j] - m1[j] * s;
#pragma unroll
        for (int kk = 0; kk < 2; kk++)
            bfr[jt][kk] = *(const f16x8*)(W1t + (size_t)j * 64 + kk * 32 + q * 8);
    }
    float pool8[8];
#pragma unroll
    for (int jt = 0; jt < 8; jt++) pool8[jt] = 0.f;

    for (int i = 0; i < 8; i++) {
        int tau = bt * 32 + w * 8 + i;
        if (tau >= TILES_PT) break;
        int nb = tau * 16;
        const __half* vrow = vh + (tb + nb + col) * 64;
        f16x8 a0 = *(const f16x8*)(vrow + q * 8);
        f16x8 a1 = *(const f16x8*)(vrow + 32 + q * 8);
        float4 af = ((const float4*)(alpha + tb + nb))[q];
#pragma unroll
        for (int jt = 0; jt < 8; jt++) {
            f32x4 acc = {0.f, 0.f, 0.f, 0.f};
            acc = __builtin_amdgcn_mfma_f32_16x16x32_f16(a0, bfr[jt][0], acc, 0, 0, 0);
            acc = __builtin_amdgcn_mfma_f32_16x16x32_f16(a1, bfr[jt][1], acc, 0, 0, 0);
            float s = sbv[jt], sh = stv[jt];
            pool8[jt] += fmaxf(s * acc[0] + sh, 0.f) * af.x
                       + fmaxf(s * acc[1] + sh, 0.f) * af.y
                       + fmaxf(s * acc[2] + sh, 0.f) * af.z
                       + fmaxf(s * acc[3] + sh, 0.f) * af.w;
        }
    }
#pragma unroll
    for (int jt = 0; jt < 8; jt++) {
        pool8[jt] += __shfl_xor(pool8[jt], 16);
        pool8[jt] += __shfl_xor(pool8[jt], 32);
    }
    if (lane < 16) {
#pragma unroll
        for (int jt = 0; jt < 8; jt++)
            atomicAdd(&pooled[t * 128 + jt * 16 + lane], pool8[jt]);
    }
}

// K6a: warm every XCD's L2 with the recurrence weights (768 KB).
__global__ __launch_bounds__(256) void k_warm(const float* __restrict__ a,
                                              const float* __restrict__ b,
                                              const float* __restrict__ c,
                                              float* __restrict__ sink) {
    int slice = blockIdx.x >> 3;           // 0..7, 24576 floats each
    int start = slice * 24576;
    float s = 0.f;
    for (int i = start + threadIdx.x; i < start + 24576; i += 256) {
        float v;
        if (i < 65536) v = a[i];
        else if (i < 131072) v = b[i - 65536];
        else v = c[i - 131072];
        s += v;
    }
    sink[blockIdx.x * 256 + threadIdx.x] = s;
}

// K6b: emb = bn2(pooled/N @ W2 + b2) and layer-0 x-part gates.
__global__ __launch_bounds__(512) void k_emb(
    const float* __restrict__ pooled,
    const float* __restrict__ W2, const float* __restrict__ b2,
    const float* __restrict__ g2, const float* __restrict__ be2,
    const float* __restrict__ m2, const float* __restrict__ v2,
    const float* __restrict__ Wih0, const float* __restrict__ bih0,
    const float* __restrict__ bhh0, float* __restrict__ gx0_g) {
    const int t = blockIdx.x, tid = threadIdx.x;
    __shared__ float pm[128];
    __shared__ float es[128];
    if (tid < 128) pm[tid] = pooled[t * 128 + tid] * (1.0f / N);
    __syncthreads();
    if (tid < 128) {
        float s = g2[tid] * rsqrtf(v2[tid] + EPS);
        float sh = be2[tid] - m2[tid] * s;
        float dot = 0.f;
#pragma unroll 8
        for (int k = 0; k < 128; k++) dot += pm[k] * W2[k * 128 + tid];
        es[tid] = s * (dot + b2[tid]) + sh;
    }
    __syncthreads();
    float dot = bih0[tid] + bhh0[tid];
    const float4* w = (const float4*)(Wih0 + tid * 128);
    const float4* e4 = (const float4*)es;
#pragma unroll
    for (int k4 = 0; k4 < 32; k4++) {
        float4 a = w[k4], bb = e4[k4];
        dot += a.x * bb.x + a.y * bb.y + a.z * bb.z + a.w * bb.w;
    }
    gx0_g[t * 512 + tid] = dot;
}

// K6c: single block, 1024 threads. Thread (r = tid&511, hf = tid>>9) owns a
// HALF gate row. Weights are NOT register-cached (the R17 spill trap):
// each step issues 16 independent L2-hit float4 loads — 16 waves give
// ~256 loads in flight, so each step is L2-BW-bound (~0.3 µs), no scratch.
__global__ __launch_bounds__(1024) void k_head(
    const float* __restrict__ gx0_g,
    const float* __restrict__ Whh0, const float* __restrict__ Whh1,
    const float* __restrict__ Wih1, const float* __restrict__ bih1,
    const float* __restrict__ bhh1,
    const float* __restrict__ Wc, const float* __restrict__ bc,
    float* __restrict__ out) {
    __shared__ float gx0[T][512];
    __shared__ float gx1h[2][T][512];
    __shared__ float ys[T][128];
    __shared__ float h[128];
    __shared__ float part[1024];
    const int tid = threadIdx.x;
    const int r = tid & 511, hf = tid >> 9;

    for (int i = tid; i < T * 512; i += 1024) gx0[i >> 9][i & 511] = gx0_g[i];
    if (tid < 128) h[tid] = 0.f;
    float c = 0.f;
    __syncthreads();

    // LSTM layer 0
    {
        const float4* wrow = (const float4*)(Whh0 + r * 128 + hf * 64);
        for (int t = 0; t < T; t++) {
            const float4* h4 = ((const float4*)h) + hf * 16;
            float dot = 0.f;
#pragma unroll
            for (int k = 0; k < 16; k++) {
                float4 wv = wrow[k];
                float4 hv = h4[k];
                dot += wv.x * hv.x + wv.y * hv.y + wv.z * hv.z + wv.w * hv.w;
            }
            part[tid] = dot;
            __syncthreads();
            if (tid < 128) {
                float i_ = gx0[t][tid]       + part[tid]       + part[512 + tid];
                float f_ = gx0[t][128 + tid] + part[128 + tid] + part[640 + tid];
                float g_ = gx0[t][256 + tid] + part[256 + tid] + part[768 + tid];
                float o_ = gx0[t][384 + tid] + part[384 + tid] + part[896 + tid];
                c = sigm(f_) * c + sigm(i_) * tanhf(g_);
                float hv = sigm(o_) * tanhf(c);
                h[tid] = hv;
                ys[t][tid] = hv;
            }
            __syncthreads();
        }
    }

    // gx1 halves: gx1h[hf][t][r] = Wih1[r][hf-half]·ys[t] (+bias in hf 0)
    {
        const float4* wrow = (const float4*)(Wih1 + r * 128 + hf * 64);
        float bias = (hf == 0) ? (bih1[r] + bhh1[r]) : 0.f;
        for (int t = 0; t < T; t++) {
            const float4* y4 = ((const float4*)ys[t]) + hf * 16;
            float dot = bias;
#pragma unroll
            for (int k = 0; k < 16; k++) {
                float4 wv = wrow[k];
                float4 yv = y4[k];
                dot += wv.x * yv.x + wv.y * yv.y + wv.z * yv.z + wv.w * yv.w;
            }
            gx1h[hf][t][r] = dot;
        }
    }

    // LSTM layer 1
    if (tid < 128) h[tid] = 0.f;
    c = 0.f;
    __syncthreads();
    {
        const float4* wrow = (const float4*)(Whh1 + r * 128 + hf * 64);
        for (int t = 0; t < T; t++) {
            const float4* h4 = ((const float4*)h) + hf * 16;
            float dot = 0.f;
#pragma unroll
            for (int k = 0; k < 16; k++) {
                float4 wv = wrow[k];
                float4 hv = h4[k];
                dot += wv.x * hv.x + wv.y * hv.y + wv.z * hv.z + wv.w * hv.w;
            }
            part[tid] = dot;
            __syncthreads();
            if (tid < 128) {
                float i_ = gx1h[0][t][tid]       + gx1h[1][t][tid]       + part[tid]       + part[512 + tid];
                float f_ = gx1h[0][t][128 + tid] + gx1h[1][t][128 + tid] + part[128 + tid] + part[640 + tid];
                float g_ = gx1h[0][t][256 + tid] + gx1h[1][t][256 + tid] + part[256 + tid] + part[768 + tid];
                float o_ = gx1h[0][t][384 + tid] + gx1h[1][t][384 + tid] + part[384 + tid] + part[896 + tid];
                c = sigm(f_) * c + sigm(i_) * tanhf(g_);
                h[tid] = sigm(o_) * tanhf(c);
            }
            __syncthreads();
        }
    }

    if (tid < 2) {
        float dot = bc[tid];
#pragma unroll 8
        for (int k = 0; k < 128; k++) dot += h[k] * Wc[tid * 128 + k];
        out[tid] = dot;
    }
    if (tid < 128) out[2 + tid] = h[tid];
}

// ---------------------------------------------------------------------------
extern "C" void kernel_launch(void* const* d_in, const int* in_sizes, int n_in,
                              void* d_out, int out_size, void* d_ws, size_t ws_size,
                              hipStream_t stream) {
    const float* x    = (const float*)d_in[0];
    const int*   edges= (const int*)d_in[1];
    const float* W1   = (const float*)d_in[2];
    const float* b1   = (const float*)d_in[3];
    const float* g1   = (const float*)d_in[4];
    const float* be1  = (const float*)d_in[5];
    const float* m1   = (const float*)d_in[6];
    const float* v1   = (const float*)d_in[7];
    const float* W2   = (const float*)d_in[8];
    const float* b2   = (const float*)d_in[9];
    const float* g2   = (const float*)d_in[10];
    const float* be2  = (const float*)d_in[11];
    const float* m2   = (const float*)d_in[12];
    const float* v2   = (const float*)d_in[13];
    const float* Wih0 = (const float*)d_in[14];
    const float* Whh0 = (const float*)d_in[15];
    const float* bih0 = (const float*)d_in[16];
    const float* bhh0 = (const float*)d_in[17];
    const float* Wih1 = (const float*)d_in[18];
    const float* Whh1 = (const float*)d_in[19];
    const float* bih1 = (const float*)d_in[20];
    const float* bhh1 = (const float*)d_in[21];
    const float* Wc   = (const float*)d_in[22];
    const float* bc   = (const float*)d_in[23];

    char* base = (char*)d_ws;
    // Aliasing: hist_g [0, 10.24 MB) dead after k_colsum; bpart
    // [10.24, 20.48 MB) written in k_partA, read by k_place AND k_wsum, then
    // dead; vh [0, 20.48 MB) written in k_gather (after colsum/place/wsum).
    unsigned int* hist_g = (unsigned int*)base;                       // T*NBA*NPACK u32
    unsigned int* bpart  = (unsigned int*)(base + (size_t)T * NBA * NPACK * 4);
    __half*       vh     = (__half*)base;                             // T*N*64 f16
    char* p = base + (size_t)T * NBA * NPACK * 4 + (size_t)T * NBUK * CHUNKA * 4;
    __half* xh   = (__half*)p;              p += (size_t)T * N * 64 * 2;  // 20.5 MB
    int*   offs  = (int*)p;                 p += (size_t)(T * N + 1) * 4 + 12; // keep 16B align
    int*   dega  = (int*)p;                 p += (size_t)T * N * 4;
    float* dinv  = (float*)p;               p += (size_t)T * N * 4;
    float* alpha = (float*)p;               p += (size_t)T * N * 4;
    int*   tot   = (int*)p;                 p += (size_t)T * N * 4;   // warm sink
    int*   eidx  = (int*)p;                 p += (size_t)T * E * 4;   // 10.25 MB
    float* wpart = (float*)p;               p += (size_t)T * NBUK * N * 4; // 20.5 MB
    int*   bcnt  = (int*)p;                 p += (size_t)T * NBUK * NBUK * 4;
    float* pooled= (float*)p;               p += (size_t)T * 128 * 4;
    float* gx0_g = (float*)p;               p += (size_t)T * 512 * 4;
    __half* W1t  = (__half*)p;

    (void)hipMemsetAsync(pooled, 0, T * 128 * sizeof(float), stream);

    k_prepw<<<32, 256, 0, stream>>>(W1, W1t);
    k_partA<<<T * NBUK, 1024, 0, stream>>>(edges, hist_g, bpart, bcnt);
    k_colsum<<<(T * NPACK + 255) / 256, 256, 0, stream>>>(hist_g, dega, dinv);
    k_scanN<<<T, 1024, 0, stream>>>(dega, offs);
    k_cvt<<<(T * N * 16 + 255) / 256, 256, 0, stream>>>(x, dinv, xh);
    k_place<<<T * NBUK, 1024, 0, stream>>>(bpart, bcnt, offs, eidx);
    k_wsum<<<T * NBUK, 1024, 0, stream>>>(bpart, dinv, wpart);
    k_wred<<<(T * N + 255) / 256, 256, 0, stream>>>(wpart, dinv, alpha);
    k_gather<<<(T * N) / 4, 256, 0, stream>>>(eidx, offs, dinv, xh, vh);
    k_mfma_pool<<<8 * 40, 256, 0, stream>>>(vh, alpha, W1t, b1, g1, be1, m1, v1, pooled);

    k_warm<<<64, 256, 0, stream>>>(Whh0, Whh1, Wih1, (float*)tot);
    k_emb<<<T, 512, 0, stream>>>(pooled, W2, b2, g2, be2, m2, v2, Wih0, bih0, bhh0, gx0_g);
    k_head<<<1, 1024, 0, stream>>>(gx0_g, Whh0, Whh1, Wih1, bih1, bhh1, Wc, bc, (float*)d_out);
}

// Round 19
// 372.581 us; speedup vs baseline: 1.1070x; 1.0514x over previous
//
#include <hip/hip_runtime.h>
#include <hip/hip_fp16.h>
#include <math.h>

#define T 8
#define N 20000
#define E 320000
#define EPS 1e-5f
#define NBA 32         // agg-item sort blocks per t
#define CHUNKA 10000   // E/32 items per block
#define NPACK 10000    // N/2 packed u32 (2 x u16 counters)
#define TILES_PT 1250  // 16-node MFMA tiles per t
#define BW 625         // nodes per dst-bucket
#define NBUK 32        // dst-buckets per t
#define SPAN_MAX 13824 // LDS stage cap (mean span 10000, sigma ~100)

typedef _Float16 f16x8 __attribute__((ext_vector_type(8)));
typedef float f32x4 __attribute__((ext_vector_type(4)));

__device__ __forceinline__ float sigm(float x) { return 1.0f / (1.0f + expf(-x)); }

// ---------------------------------------------------------------------------
// K0: W1t[j][k] = half(W1[k][j])  (fp16 transposed weights for MFMA B-frags)
__global__ __launch_bounds__(256) void k_prepw(const float* __restrict__ W1,
                                               __half* __restrict__ W1t) {
    int i = blockIdx.x * 256 + threadIdx.x;
    if (i >= 64 * 128) return;
    int j = i & 127, k = i >> 7;
    W1t[j * 64 + k] = __float2half(W1[i]);
}

// K1: partition pass (merged hist). One read of the keys produces BOTH the
// per-node packed histogram (-> hist_g for colsum) and per-bucket counts;
// a second read bins items (full dst<<15 | src) into LDS and writes the
// bucket-ordered run coalesced. Zero scattered global stores.
__global__ __launch_bounds__(1024) void k_partA(const int* __restrict__ edges,
                                                unsigned int* __restrict__ hist_g,
                                                unsigned int* __restrict__ bpart,
                                                int* __restrict__ bcnt) {
    __shared__ unsigned int arr[CHUNKA];   // 40 KB: hist, then stage
    __shared__ int cnt[NBUK], cur[NBUK];
    const int t = blockIdx.x & 7, b = blockIdx.x >> 3;
    const int tid = threadIdx.x;
    const int* keys = edges + (size_t)t * 2 * E + E + b * CHUNKA;   // dst
    const int* pays = edges + (size_t)t * 2 * E + b * CHUNKA;       // src
    for (int i = tid; i < NPACK; i += 1024) arr[i] = 0;
    if (tid < NBUK) cnt[tid] = 0;
    __syncthreads();
    for (int i = tid; i < CHUNKA; i += 1024) {
        int k = keys[i];
        atomicAdd(&arr[k >> 1], 1u << ((k & 1) * 16));
        atomicAdd(&cnt[k / BW], 1);
    }
    __syncthreads();
    unsigned int* hout = hist_g + (size_t)(t * NBA + b) * NPACK;
    for (int i = tid; i < NPACK; i += 1024) hout[i] = arr[i];
    if (tid == 0) {
        int run = 0;
        for (int u = 0; u < NBUK; u++) { cur[u] = run; run += cnt[u]; }
    }
    if (tid < NBUK) bcnt[(t * NBUK + tid) * NBUK + b] = cnt[tid];
    __syncthreads();
    for (int i = tid; i < CHUNKA; i += 1024) {
        int k = keys[i];
        int p = pays[i];
        int slot = atomicAdd(&cur[k / BW], 1);
        arr[slot] = ((unsigned int)k << 15) | (unsigned int)p;
    }
    __syncthreads();
    unsigned int* outp = bpart + (size_t)(t * NBUK + b) * CHUNKA;
    for (int i = tid; i < CHUNKA; i += 1024) outp[i] = arr[i];
}

// K2a: column sum over the 32 agg blocks — dega = in-degree; dinv.
__global__ __launch_bounds__(256) void k_colsum(
    const unsigned int* __restrict__ hist_g,
    int* __restrict__ dega, float* __restrict__ dinv) {
    int idx = blockIdx.x * 256 + threadIdx.x;
    if (idx >= T * NPACK) return;
    int t = idx / NPACK, i = idx - t * NPACK;
    const unsigned int* hp = hist_g + (size_t)t * NBA * NPACK + i;
    unsigned int a0 = 0, a1 = 0;
#pragma unroll
    for (int b = 0; b < NBA; b++) {
        unsigned int h = hp[(size_t)b * NPACK];
        a0 += h & 0xffffu; a1 += h >> 16;
    }
    int n0 = t * N + 2 * i;
    dega[n0]     = (int)a0;
    dega[n0 + 1] = (int)a1;
    dinv[n0]     = rsqrtf((float)a0 + 1.0f);
    dinv[n0 + 1] = rsqrtf((float)a1 + 1.0f);
}

// K2b: per-t exclusive prefix over node in-degrees -> offs (+ sentinel).
__global__ __launch_bounds__(1024) void k_scanN(const int* __restrict__ dega,
                                                int* __restrict__ offs) {
    const int t = blockIdx.x, tid = threadIdx.x;
    __shared__ int sh[1024];
    int local[20];
    int sum = 0;
    if (tid < 1000) {
        const int* tp = dega + t * N + tid * 20;
#pragma unroll
        for (int i = 0; i < 20; i++) { local[i] = tp[i]; sum += local[i]; }
    }
    sh[tid] = sum;
    __syncthreads();
    for (int off = 1; off < 1024; off <<= 1) {
        int v = (tid >= off) ? sh[tid - off] : 0;
        __syncthreads();
        sh[tid] += v;
        __syncthreads();
    }
    if (tid < 1000) {
        int run = t * E + sh[tid] - sum;
        int* op = offs + t * N + tid * 20;
#pragma unroll
        for (int i = 0; i < 20; i++) { op[i] = run; run += local[i]; }
    }
    if (t == T - 1 && tid == 0) offs[T * N] = T * E;
}

// K2d: xh[t][n][k] = half(dinv[t][n] * x[t][n][k]). per-t slice 2.56 MB.
__global__ __launch_bounds__(256) void k_cvt(const float* __restrict__ x,
                                             const float* __restrict__ dinv,
                                             __half* __restrict__ xh) {
    int idx = blockIdx.x * 256 + threadIdx.x;   // one float4 per thread
    if (idx >= T * N * 16) return;
    float d = dinv[idx >> 4];
    float4 vv = ((const float4*)x)[idx];
    __half h0 = __float2half(vv.x * d);
    __half h1 = __float2half(vv.y * d);
    __half h2 = __float2half(vv.z * d);
    __half h3 = __float2half(vv.w * d);
    ushort4 pack;
    pack.x = *(unsigned short*)&h0;
    pack.y = *(unsigned short*)&h1;
    pack.z = *(unsigned short*)&h2;
    pack.w = *(unsigned short*)&h3;
    ((ushort4*)xh)[idx] = pack;
}

// K3b: placement pass. One block per (t,bucket): gathers the bucket's items
// from the 32 per-block runs (coalesced reads), resolves CSR positions via
// 625 LDS cursors, stages the segment in LDS, writes it out as FULL LINES.
// Payload: src*32 (u32/half2 row offset for the packed gather).
__global__ __launch_bounds__(1024) void k_place(const unsigned int* __restrict__ bpart,
                                                const int* __restrict__ bcnt,
                                                const int* __restrict__ offs,
                                                int* __restrict__ eidx) {
    __shared__ int stage[SPAN_MAX];          // 54 KB
    __shared__ int cursor[BW];
    __shared__ int offb[NBUK], lenb[NBUK];
    const int t = blockIdx.x & 7, u = blockIdx.x >> 3;
    const int tid = threadIdx.x;
    const int nodeBase = t * N + u * BW;
    const int dstBase = u * BW;
    const int segStart = offs[nodeBase];
    const int segEnd = offs[nodeBase + BW];
    const int span = segEnd - segStart;
    if (tid < NBUK) {
        int s = 0;
        for (int uu = 0; uu < u; uu++) s += bcnt[(t * NBUK + uu) * NBUK + tid];
        offb[tid] = s;
        lenb[tid] = bcnt[(t * NBUK + u) * NBUK + tid];
    }
    for (int j = tid; j < BW; j += 1024) cursor[j] = offs[nodeBase + j] - segStart;
    __syncthreads();
    if (span <= SPAN_MAX) {
        for (int b = 0; b < NBUK; b++) {
            const unsigned int* src = bpart + (size_t)(t * NBUK + b) * CHUNKA + offb[b];
            int len = lenb[b];
            for (int i = tid; i < len; i += 1024) {
                unsigned int it = src[i];
                int pos = atomicAdd(&cursor[(int)(it >> 15) - dstBase], 1);
                stage[pos] = (int)(it & 0x7fffu) << 5;
            }
            __syncthreads();
        }
        int* out = eidx + segStart;
        for (int i = tid; i < span; i += 1024) out[i] = stage[i];
    } else {                                  // statistically unreachable fallback
        for (int b = 0; b < NBUK; b++) {
            const unsigned int* src = bpart + (size_t)(t * NBUK + b) * CHUNKA + offb[b];
            int len = lenb[b];
            for (int i = tid; i < len; i += 1024) {
                unsigned int it = src[i];
                int pos = atomicAdd(&cursor[(int)(it >> 15) - dstBase], 1);
                eidx[segStart + pos] = (int)(it & 0x7fffu) << 5;
            }
            __syncthreads();
        }
    }
}

// K3c: w-sum from the coalesced bpart runs: wacc[src] += dinv[dst].
__global__ __launch_bounds__(1024) void k_wsum(const unsigned int* __restrict__ bpart,
                                               const float* __restrict__ dinv,
                                               float* __restrict__ wpart) {
    __shared__ float wf[NPACK];              // 40 KB
    const int t = blockIdx.x & 7, b = blockIdx.x >> 3;
    const int tid = threadIdx.x;
    const unsigned int* run = bpart + (size_t)(t * NBUK + b) * CHUNKA;
    const float* dv = dinv + t * N;
    for (int half = 0; half < 2; half++) {
        for (int i = tid; i < NPACK; i += 1024) wf[i] = 0.f;
        __syncthreads();
        int lo = half * NPACK;
        for (int i = tid; i < CHUNKA; i += 1024) {
            unsigned int it = run[i];
            int q = (int)(it & 0x7fffu) - lo;
            if (q >= 0 && q < NPACK) atomicAdd(&wf[q], dv[it >> 15]);
        }
        __syncthreads();
        float* out = wpart + (size_t)(t * NBUK + b) * N + lo;
        for (int i = tid; i < NPACK; i += 1024) out[i] = wf[i];
        __syncthreads();
    }
}

// K3d: alpha[t][n] = dinv*(sum_b wpart + dinv). Coalesced 32-way reduce.
__global__ __launch_bounds__(256) void k_wred(const float* __restrict__ wpart,
                                              const float* __restrict__ dinv,
                                              float* __restrict__ alpha) {
    int node = blockIdx.x * 256 + threadIdx.x;
    if (node >= T * N) return;
    int t = node / N, n = node - t * N;
    float s = 0.f;
#pragma unroll
    for (int b = 0; b < NBUK; b++) s += wpart[(size_t)(t * NBUK + b) * N + n];
    float di = dinv[node];
    alpha[node] = di * (s + di);
}

// K4: gather — one wave per node; lane = (g = edge parity, f = feature pair).
// Packed fp16 accumulation: each 64-item block accumulates in a __half2 via
// v_pk_add_f16 (8 pk_adds per 16 edges -> 1.5 inst/edge), converted to the
// fp32 accumulators once per block. ~32 tree-grouped fp16 adds per lane-block
// keeps rounding ~1e-5 at the pooled output (threshold 3.8e-4).
__global__ __launch_bounds__(256) void k_gather(
    const int* __restrict__ eidx, const int* __restrict__ offs,
    const float* __restrict__ dinv, const __half* __restrict__ xh,
    __half* __restrict__ vh) {
    const int t = blockIdx.x & 7;
    const int n = ((blockIdx.x >> 3) << 2) + (threadIdx.x >> 6);
    const int lane = threadIdx.x & 63;
    const int f = lane & 31, g = lane >> 5;
    if (n >= N) return;
    const int node = t * N + n;
    const int start = offs[node];
    const int end = offs[node + 1];
    const __half2* xt2 = (const __half2*)(xh + (size_t)t * N * 64);
    float acc0 = 0.f, acc1 = 0.f;
    for (int bs = start; bs < end; bs += 64) {
        int cnt = end - bs; if (cnt > 64) cnt = 64;
        int idx = 0;
        if (lane < cnt) idx = __builtin_nontemporal_load(&eidx[bs + lane]);
        __half2 hacc = __float2half2_rn(0.f);
        int e = 0;
        for (; e + 15 < cnt; e += 16) {
            int o0 = __shfl(idx, e + 0 + g),  o1 = __shfl(idx, e + 2 + g);
            int o2 = __shfl(idx, e + 4 + g),  o3 = __shfl(idx, e + 6 + g);
            int o4 = __shfl(idx, e + 8 + g),  o5 = __shfl(idx, e + 10 + g);
            int o6 = __shfl(idx, e + 12 + g), o7 = __shfl(idx, e + 14 + g);
            __half2 u0 = xt2[o0 + f], u1 = xt2[o1 + f];
            __half2 u2 = xt2[o2 + f], u3 = xt2[o3 + f];
            __half2 u4 = xt2[o4 + f], u5 = xt2[o5 + f];
            __half2 u6 = xt2[o6 + f], u7 = xt2[o7 + f];
            __half2 s01 = __hadd2(u0, u1), s23 = __hadd2(u2, u3);
            __half2 s45 = __hadd2(u4, u5), s67 = __hadd2(u6, u7);
            __half2 s03 = __hadd2(s01, s23), s47 = __hadd2(s45, s67);
            hacc = __hadd2(hacc, __hadd2(s03, s47));
        }
        for (; e + 1 < cnt; e += 2) {
            int o = __shfl(idx, e + g);
            hacc = __hadd2(hacc, xt2[o + f]);
        }
        if (e < cnt) {
            int o = __shfl(idx, e);
            if (g == 0) hacc = __hadd2(hacc, xt2[o + f]);
        }
        float2 fa = __half22float2(hacc);
        acc0 += fa.x;
        acc1 += fa.y;
    }
    acc0 += __shfl_down(acc0, 32);
    acc1 += __shfl_down(acc1, 32);
    if (g == 0) {
        float di = dinv[node];
        float2 us = __half22float2(xt2[(n << 5) + f]);
        float r0 = di * (acc0 + us.x);
        float r1 = di * (acc1 + us.y);
        __half2 outp = __floats2half2_rn(r0, r1);
        ((__half2*)vh)[(size_t)node * 32 + f] = outp;
    }
}

// K5: MFMA layer-1 GEMM (fp16 in, fp32 acc) + BN/ReLU + alpha-pool.
__global__ __launch_bounds__(256) void k_mfma_pool(
    const __half* __restrict__ vh, const float* __restrict__ alpha,
    const __half* __restrict__ W1t,
    const float* __restrict__ b1, const float* __restrict__ g1,
    const float* __restrict__ be1, const float* __restrict__ m1,
    const float* __restrict__ v1, float* __restrict__ pooled) {
    const int t = blockIdx.x & 7;
    const int bt = blockIdx.x >> 3;
    const int w = threadIdx.x >> 6, lane = threadIdx.x & 63;
    const int q = lane >> 4, col = lane & 15;
    const size_t tb = (size_t)t * N;

    f16x8 bfr[8][2];
    float sbv[8], stv[8];
#pragma unroll
    for (int jt = 0; jt < 8; jt++) {
        int j = jt * 16 + col;
        float s = g1[j] * rsqrtf(v1[j] + EPS);
        sbv[jt] = s;
        stv[jt] = s * b1[j] + be1[j] - m1[j] * s;
#pragma unroll
        for (int kk = 0; kk < 2; kk++)
            bfr[jt][kk] = *(const f16x8*)(W1t + (size_t)j * 64 + kk * 32 + q * 8);
    }
    float pool8[8];
#pragma unroll
    for (int jt = 0; jt < 8; jt++) pool8[jt] = 0.f;

    for (int i = 0; i < 8; i++) {
        int tau = bt * 32 + w * 8 + i;
        if (tau >= TILES_PT) break;
        int nb = tau * 16;
        const __half* vrow = vh + (tb + nb + col) * 64;
        f16x8 a0 = *(const f16x8*)(vrow + q * 8);
        f16x8 a1 = *(const f16x8*)(vrow + 32 + q * 8);
        float4 af = ((const float4*)(alpha + tb + nb))[q];
#pragma unroll
        for (int jt = 0; jt < 8; jt++) {
            f32x4 acc = {0.f, 0.f, 0.f, 0.f};
            acc = __builtin_amdgcn_mfma_f32_16x16x32_f16(a0, bfr[jt][0], acc, 0, 0, 0);
            acc = __builtin_amdgcn_mfma_f32_16x16x32_f16(a1, bfr[jt][1], acc, 0, 0, 0);
            float s = sbv[jt], sh = stv[jt];
            pool8[jt] += fmaxf(s * acc[0] + sh, 0.f) * af.x
                       + fmaxf(s * acc[1] + sh, 0.f) * af.y
                       + fmaxf(s * acc[2] + sh, 0.f) * af.z
                       + fmaxf(s * acc[3] + sh, 0.f) * af.w;
        }
    }
#pragma unroll
    for (int jt = 0; jt < 8; jt++) {
        pool8[jt] += __shfl_xor(pool8[jt], 16);
        pool8[jt] += __shfl_xor(pool8[jt], 32);
    }
    if (lane < 16) {
#pragma unroll
        for (int jt = 0; jt < 8; jt++)
            atomicAdd(&pooled[t * 128 + jt * 16 + lane], pool8[jt]);
    }
}

// K6a: warm every XCD's L2 with the recurrence weights (768 KB).
__global__ __launch_bounds__(256) void k_warm(const float* __restrict__ a,
                                              const float* __restrict__ b,
                                              const float* __restrict__ c,
                                              float* __restrict__ sink) {
    int slice = blockIdx.x >> 3;           // 0..7, 24576 floats each
    int start = slice * 24576;
    float s = 0.f;
    for (int i = start + threadIdx.x; i < start + 24576; i += 256) {
        float v;
        if (i < 65536) v = a[i];
        else if (i < 131072) v = b[i - 65536];
        else v = c[i - 131072];
        s += v;
    }
    sink[blockIdx.x * 256 + threadIdx.x] = s;
}

// K6b: emb = bn2(pooled/N @ W2 + b2) and layer-0 x-part gates.
__global__ __launch_bounds__(512) void k_emb(
    const float* __restrict__ pooled,
    const float* __restrict__ W2, const float* __restrict__ b2,
    const float* __restrict__ g2, const float* __restrict__ be2,
    const float* __restrict__ m2, const float* __restrict__ v2,
    const float* __restrict__ Wih0, const float* __restrict__ bih0,
    const float* __restrict__ bhh0, float* __restrict__ gx0_g) {
    const int t = blockIdx.x, tid = threadIdx.x;
    __shared__ float pm[128];
    __shared__ float es[128];
    if (tid < 128) pm[tid] = pooled[t * 128 + tid] * (1.0f / N);
    __syncthreads();
    if (tid < 128) {
        float s = g2[tid] * rsqrtf(v2[tid] + EPS);
        float sh = be2[tid] - m2[tid] * s;
        float dot = 0.f;
#pragma unroll 8
        for (int k = 0; k < 128; k++) dot += pm[k] * W2[k * 128 + tid];
        es[tid] = s * (dot + b2[tid]) + sh;
    }
    __syncthreads();
    float dot = bih0[tid] + bhh0[tid];
    const float4* w = (const float4*)(Wih0 + tid * 128);
    const float4* e4 = (const float4*)es;
#pragma unroll
    for (int k4 = 0; k4 < 32; k4++) {
        float4 a = w[k4], bb = e4[k4];
        dot += a.x * bb.x + a.y * bb.y + a.z * bb.z + a.w * bb.w;
    }
    gx0_g[t * 512 + tid] = dot;
}

// K6c: single block, 1024 threads. Thread (r = tid&511, hf = tid>>9) owns a
// HALF gate row. Weights are NOT register-cached (the R17 spill trap):
// each step issues 16 independent L2-hit float4 loads — 16 waves give
// ~256 loads in flight, so each step is L2-BW-bound (~0.3 µs), no scratch.
__global__ __launch_bounds__(1024) void k_head(
    const float* __restrict__ gx0_g,
    const float* __restrict__ Whh0, const float* __restrict__ Whh1,
    const float* __restrict__ Wih1, const float* __restrict__ bih1,
    const float* __restrict__ bhh1,
    const float* __restrict__ Wc, const float* __restrict__ bc,
    float* __restrict__ out) {
    __shared__ float gx0[T][512];
    __shared__ float gx1h[2][T][512];
    __shared__ float ys[T][128];
    __shared__ float h[128];
    __shared__ float part[1024];
    const int tid = threadIdx.x;
    const int r = tid & 511, hf = tid >> 9;

    for (int i = tid; i < T * 512; i += 1024) gx0[i >> 9][i & 511] = gx0_g[i];
    if (tid < 128) h[tid] = 0.f;
    float c = 0.f;
    __syncthreads();

    // LSTM layer 0
    {
        const float4* wrow = (const float4*)(Whh0 + r * 128 + hf * 64);
        for (int t = 0; t < T; t++) {
            const float4* h4 = ((const float4*)h) + hf * 16;
            float dot = 0.f;
#pragma unroll
            for (int k = 0; k < 16; k++) {
                float4 wv = wrow[k];
                float4 hv = h4[k];
                dot += wv.x * hv.x + wv.y * hv.y + wv.z * hv.z + wv.w * hv.w;
            }
            part[tid] = dot;
            __syncthreads();
            if (tid < 128) {
                float i_ = gx0[t][tid]       + part[tid]       + part[512 + tid];
                float f_ = gx0[t][128 + tid] + part[128 + tid] + part[640 + tid];
                float g_ = gx0[t][256 + tid] + part[256 + tid] + part[768 + tid];
                float o_ = gx0[t][384 + tid] + part[384 + tid] + part[896 + tid];
                c = sigm(f_) * c + sigm(i_) * tanhf(g_);
                float hv = sigm(o_) * tanhf(c);
                h[tid] = hv;
                ys[t][tid] = hv;
            }
            __syncthreads();
        }
    }

    // gx1 halves: gx1h[hf][t][r] = Wih1[r][hf-half]·ys[t] (+bias in hf 0)
    {
        const float4* wrow = (const float4*)(Wih1 + r * 128 + hf * 64);
        float bias = (hf == 0) ? (bih1[r] + bhh1[r]) : 0.f;
        for (int t = 0; t < T; t++) {
            const float4* y4 = ((const float4*)ys[t]) + hf * 16;
            float dot = bias;
#pragma unroll
            for (int k = 0; k < 16; k++) {
                float4 wv = wrow[k];
                float4 yv = y4[k];
                dot += wv.x * yv.x + wv.y * yv.y + wv.z * yv.z + wv.w * yv.w;
            }
            gx1h[hf][t][r] = dot;
        }
    }

    // LSTM layer 1
    if (tid < 128) h[tid] = 0.f;
    c = 0.f;
    __syncthreads();
    {
        const float4* wrow = (const float4*)(Whh1 + r * 128 + hf * 64);
        for (int t = 0; t < T; t++) {
            const float4* h4 = ((const float4*)h) + hf * 16;
            float dot = 0.f;
#pragma unroll
            for (int k = 0; k < 16; k++) {
                float4 wv = wrow[k];
                float4 hv = h4[k];
                dot += wv.x * hv.x + wv.y * hv.y + wv.z * hv.z + wv.w * hv.w;
            }
            part[tid] = dot;
            __syncthreads();
            if (tid < 128) {
                float i_ = gx1h[0][t][tid]       + gx1h[1][t][tid]       + part[tid]       + part[512 + tid];
                float f_ = gx1h[0][t][128 + tid] + gx1h[1][t][128 + tid] + part[128 + tid] + part[640 + tid];
                float g_ = gx1h[0][t][256 + tid] + gx1h[1][t][256 + tid] + part[256 + tid] + part[768 + tid];
                float o_ = gx1h[0][t][384 + tid] + gx1h[1][t][384 + tid] + part[384 + tid] + part[896 + tid];
                c = sigm(f_) * c + sigm(i_) * tanhf(g_);
                h[tid] = sigm(o_) * tanhf(c);
            }
            __syncthreads();
        }
    }

    if (tid < 2) {
        float dot = bc[tid];
#pragma unroll 8
        for (int k = 0; k < 128; k++) dot += h[k] * Wc[tid * 128 + k];
        out[tid] = dot;
    }
    if (tid < 128) out[2 + tid] = h[tid];
}

// ---------------------------------------------------------------------------
extern "C" void kernel_launch(void* const* d_in, const int* in_sizes, int n_in,
                              void* d_out, int out_size, void* d_ws, size_t ws_size,
                              hipStream_t stream) {
    const float* x    = (const float*)d_in[0];
    const int*   edges= (const int*)d_in[1];
    const float* W1   = (const float*)d_in[2];
    const float* b1   = (const float*)d_in[3];
    const float* g1   = (const float*)d_in[4];
    const float* be1  = (const float*)d_in[5];
    const float* m1   = (const float*)d_in[6];
    const float* v1   = (const float*)d_in[7];
    const float* W2   = (const float*)d_in[8];
    const float* b2   = (const float*)d_in[9];
    const float* g2   = (const float*)d_in[10];
    const float* be2  = (const float*)d_in[11];
    const float* m2   = (const float*)d_in[12];
    const float* v2   = (const float*)d_in[13];
    const float* Wih0 = (const float*)d_in[14];
    const float* Whh0 = (const float*)d_in[15];
    const float* bih0 = (const float*)d_in[16];
    const float* bhh0 = (const float*)d_in[17];
    const float* Wih1 = (const float*)d_in[18];
    const float* Whh1 = (const float*)d_in[19];
    const float* bih1 = (const float*)d_in[20];
    const float* bhh1 = (const float*)d_in[21];
    const float* Wc   = (const float*)d_in[22];
    const float* bc   = (const float*)d_in[23];

    char* base = (char*)d_ws;
    // Aliasing: hist_g [0, 10.24 MB) dead after k_colsum; bpart
    // [10.24, 20.48 MB) written in k_partA, read by k_place AND k_wsum, then
    // dead; vh [0, 20.48 MB) written in k_gather (after colsum/place/wsum).
    unsigned int* hist_g = (unsigned int*)base;                       // T*NBA*NPACK u32
    unsigned int* bpart  = (unsigned int*)(base + (size_t)T * NBA * NPACK * 4);
    __half*       vh     = (__half*)base;                             // T*N*64 f16
    char* p = base + (size_t)T * NBA * NPACK * 4 + (size_t)T * NBUK * CHUNKA * 4;
    __half* xh   = (__half*)p;              p += (size_t)T * N * 64 * 2;  // 20.5 MB
    int*   offs  = (int*)p;                 p += (size_t)(T * N + 1) * 4 + 12; // keep 16B align
    int*   dega  = (int*)p;                 p += (size_t)T * N * 4;
    float* dinv  = (float*)p;               p += (size_t)T * N * 4;
    float* alpha = (float*)p;               p += (size_t)T * N * 4;
    int*   tot   = (int*)p;                 p += (size_t)T * N * 4;   // warm sink
    int*   eidx  = (int*)p;                 p += (size_t)T * E * 4;   // 10.25 MB
    float* wpart = (float*)p;               p += (size_t)T * NBUK * N * 4; // 20.5 MB
    int*   bcnt  = (int*)p;                 p += (size_t)T * NBUK * NBUK * 4;
    float* pooled= (float*)p;               p += (size_t)T * 128 * 4;
    float* gx0_g = (float*)p;               p += (size_t)T * 512 * 4;
    __half* W1t  = (__half*)p;

    (void)hipMemsetAsync(pooled, 0, T * 128 * sizeof(float), stream);

    k_prepw<<<32, 256, 0, stream>>>(W1, W1t);
    k_partA<<<T * NBUK, 1024, 0, stream>>>(edges, hist_g, bpart, bcnt);
    k_colsum<<<(T * NPACK + 255) / 256, 256, 0, stream>>>(hist_g, dega, dinv);
    k_scanN<<<T, 1024, 0, stream>>>(dega, offs);
    k_cvt<<<(T * N * 16 + 255) / 256, 256, 0, stream>>>(x, dinv, xh);
    k_place<<<T * NBUK, 1024, 0, stream>>>(bpart, bcnt, offs, eidx);
    k_wsum<<<T * NBUK, 1024, 0, stream>>>(bpart, dinv, wpart);
    k_wred<<<(T * N + 255) / 256, 256, 0, stream>>>(wpart, dinv, alpha);
    k_gather<<<(T * N) / 4, 256, 0, stream>>>(eidx, offs, dinv, xh, vh);
    k_mfma_pool<<<8 * 40, 256, 0, stream>>>(vh, alpha, W1t, b1, g1, be1, m1, v1, pooled);

    k_warm<<<64, 256, 0, stream>>>(Whh0, Whh1, Wih1, (float*)tot);
    k_emb<<<T, 512, 0, stream>>>(pooled, W2, b2, g2, be2, m2, v2, Wih0, bih0, bhh0, gx0_g);
    k_head<<<1, 1024, 0, stream>>>(gx0_g, Whh0, Whh1, Wih1, bih1, bhh1, Wc, bc, (float*)d_out);
}